// Round 2
// baseline (1823.922 us; speedup 1.0000x reference)
//
#include <hip/hip_runtime.h>
#include <hip/hip_bf16.h>
#include <math.h>

#define NN 65536          // nodes
#define NE 196608         // edges (without self loops)
#define ET (NE + NN)      // edges + self loops = 262144
#define NG 2048           // graphs
#define FIN 9
#define DD 128
#define H1 10
#define LRS 0.2f

__device__ __forceinline__ float lrelu(float v) { return v >= 0.f ? v : LRS * v; }
__device__ __forceinline__ float eluf(float v)  { return v > 0.f ? v : expm1f(v); }

// float atomic max via int max (non-negative) / uint min (negative).
__device__ __forceinline__ void atomicMaxF(float* addr, float v) {
    if (__float_as_int(v) >= 0) {
        atomicMax((int*)addr, __float_as_int(v));
    } else {
        atomicMin((unsigned int*)addr, __float_as_uint(v));
    }
}

// ---- kernel 1: fold W1 into per-head 9-dim logit vectors --------------------
// ws1[f*H1+h] = sum_c W1[f, h*128+c] * a_src1[h,c]   (same for wd1/a_dst1)
__global__ void prep_kernel(const float* __restrict__ W1,
                            const float* __restrict__ a_src1,
                            const float* __restrict__ a_dst1,
                            float* __restrict__ ws1, float* __restrict__ wd1) {
    int t = threadIdx.x;
    if (t >= FIN * H1) return;
    int f = t / H1, h = t - f * H1;
    float s = 0.f, d = 0.f;
    for (int c = 0; c < DD; ++c) {
        float w = W1[f * (H1 * DD) + h * DD + c];
        s = fmaf(w, a_src1[h * DD + c], s);
        d = fmaf(w, a_dst1[h * DD + c], d);
    }
    ws1[t] = s;
    wd1[t] = d;
}

// ---- kernel 2: per-node attention logits + init of accumulators ------------
__global__ void alpha1_kernel(const float* __restrict__ x,
                              const float* __restrict__ ws1,
                              const float* __restrict__ wd1,
                              float* __restrict__ as1, float* __restrict__ ad1,
                              float* __restrict__ m1, float* __restrict__ den1,
                              float* __restrict__ xagg1,
                              float* __restrict__ m2, float* __restrict__ den2) {
    int n = blockIdx.x * 256 + threadIdx.x;
    if (n >= NN) return;
    float xv[FIN];
#pragma unroll
    for (int f = 0; f < FIN; ++f) xv[f] = x[(size_t)n * FIN + f];
#pragma unroll
    for (int h = 0; h < H1; ++h) {
        float s = 0.f, d = 0.f;
#pragma unroll
        for (int f = 0; f < FIN; ++f) {
            s = fmaf(xv[f], ws1[f * H1 + h], s);
            d = fmaf(xv[f], wd1[f * H1 + h], d);
        }
        as1[n * H1 + h] = s;
        ad1[n * H1 + h] = d;
        m1[n * H1 + h] = -INFINITY;
        den1[n * H1 + h] = 0.f;
    }
#pragma unroll
    for (int i = 0; i < H1 * FIN; ++i) xagg1[(size_t)n * (H1 * FIN) + i] = 0.f;
    m2[n] = -INFINITY;
    den2[n] = 0.f;
}

// ---- kernel 3: zero agg2 / init pooled to -inf ------------------------------
__global__ void init2_kernel(float* __restrict__ agg2, float* __restrict__ pooled) {
    int idx = blockIdx.x * 256 + threadIdx.x;
    if (idx < NN * DD) {
        agg2[idx] = 0.f;
    } else {
        int j = idx - NN * DD;
        if (j < NG * DD) pooled[j] = -INFINITY;
    }
}

// ---- kernel 4: layer-1 segment max over edges (per edge,head) ---------------
__global__ void edge_max1(const int* __restrict__ ei,
                          const float* __restrict__ as1, const float* __restrict__ ad1,
                          float* __restrict__ m1) {
    int idx = blockIdx.x * 256 + threadIdx.x;
    if (idx >= ET * H1) return;
    int e = idx / H1, h = idx - e * H1;
    int s, d;
    if (e < NE) { s = ei[e]; d = ei[NE + e]; } else { s = e - NE; d = s; }
    float v = lrelu(as1[s * H1 + h] + ad1[d * H1 + h]);
    atomicMaxF(&m1[d * H1 + h], v);
}

// ---- kernel 5: layer-1 exp + denom + 9-dim weighted x aggregation -----------
__global__ void edge_sum1(const int* __restrict__ ei, const float* __restrict__ x,
                          const float* __restrict__ as1, const float* __restrict__ ad1,
                          const float* __restrict__ m1,
                          float* __restrict__ den1, float* __restrict__ xagg1) {
    int idx = blockIdx.x * 256 + threadIdx.x;
    if (idx >= ET * H1) return;
    int e = idx / H1, h = idx - e * H1;
    int s, d;
    if (e < NE) { s = ei[e]; d = ei[NE + e]; } else { s = e - NE; d = s; }
    float v = lrelu(as1[s * H1 + h] + ad1[d * H1 + h]);
    float ex = expf(v - m1[d * H1 + h]);
    atomicAdd(&den1[d * H1 + h], ex);
    const float* xs = &x[(size_t)s * FIN];
    float* xa = &xagg1[((size_t)d * H1 + h) * FIN];
#pragma unroll
    for (int f = 0; f < FIN; ++f) atomicAdd(&xa[f], ex * xs[f]);
}

// ---- kernel 6: fused h2 = elu(xagg1@W1/den + b1) @ W2 -----------------------
// Block: 32 nodes x 128 outputs, K = 1280. The x1 tile (32x64) is built on the
// fly in LDS from the 9-dim aggregates (saves the 168 MB x1 buffer + 336 MB of
// HBM traffic).
__global__ __launch_bounds__(256) void h2_gemm(const float* __restrict__ xagg1,
                                               const float* __restrict__ den1,
                                               const float* __restrict__ W1,
                                               const float* __restrict__ b1,
                                               const float* __restrict__ W2,
                                               float* __restrict__ h2) {
    __shared__ float Xs[32][65];
    const int n0 = blockIdx.x * 32;
    const int t = threadIdx.x;
    const int tx = t & 31, ty = t >> 5;         // compute mapping: 4 rows x 4 cols per thread
    const int jl = t & 63;                      // tile-build: column within k-tile
    const int rg = t >> 6;                      // tile-build: row group (8 rows each)
    float acc[4][4] = {};
    for (int k0 = 0; k0 < H1 * DD; k0 += 64) {
        const int h = k0 >> 7;                  // 64 | 128 -> whole tile in one head
        float w1c[FIN];
#pragma unroll
        for (int f = 0; f < FIN; ++f) w1c[f] = W1[f * (H1 * DD) + k0 + jl];
        const float b1j = b1[k0 + jl];
        __syncthreads();                        // prev-iter Xs reads done
#pragma unroll
        for (int r = 0; r < 8; ++r) {
            const int n = n0 + rg * 8 + r;
            const float* xa = &xagg1[((size_t)n * H1 + h) * FIN];
            const float scale = 1.f / (den1[n * H1 + h] + 1e-16f);
            float acc1 = b1j;
#pragma unroll
            for (int f = 0; f < FIN; ++f) acc1 = fmaf(xa[f] * scale, w1c[f], acc1);
            Xs[rg * 8 + r][jl] = eluf(acc1);
        }
        __syncthreads();
#pragma unroll 8
        for (int k = 0; k < 64; ++k) {
            float4 w = *(const float4*)&W2[(size_t)(k0 + k) * DD + tx * 4];
            float a0 = Xs[ty * 4 + 0][k];
            float a1 = Xs[ty * 4 + 1][k];
            float a2 = Xs[ty * 4 + 2][k];
            float a3 = Xs[ty * 4 + 3][k];
            acc[0][0] = fmaf(a0, w.x, acc[0][0]); acc[0][1] = fmaf(a0, w.y, acc[0][1]);
            acc[0][2] = fmaf(a0, w.z, acc[0][2]); acc[0][3] = fmaf(a0, w.w, acc[0][3]);
            acc[1][0] = fmaf(a1, w.x, acc[1][0]); acc[1][1] = fmaf(a1, w.y, acc[1][1]);
            acc[1][2] = fmaf(a1, w.z, acc[1][2]); acc[1][3] = fmaf(a1, w.w, acc[1][3]);
            acc[2][0] = fmaf(a2, w.x, acc[2][0]); acc[2][1] = fmaf(a2, w.y, acc[2][1]);
            acc[2][2] = fmaf(a2, w.z, acc[2][2]); acc[2][3] = fmaf(a2, w.w, acc[2][3]);
            acc[3][0] = fmaf(a3, w.x, acc[3][0]); acc[3][1] = fmaf(a3, w.y, acc[3][1]);
            acc[3][2] = fmaf(a3, w.z, acc[3][2]); acc[3][3] = fmaf(a3, w.w, acc[3][3]);
        }
    }
#pragma unroll
    for (int r = 0; r < 4; ++r) {
        float4 v = make_float4(acc[r][0], acc[r][1], acc[r][2], acc[r][3]);
        *(float4*)&h2[(size_t)(n0 + ty * 4 + r) * DD + tx * 4] = v;
    }
}

// ---- kernel 8: layer-2 logits (32 lanes per node, shuffle reduce) -----------
__global__ void alpha2_kernel(const float* __restrict__ h2,
                              const float* __restrict__ a_src2,
                              const float* __restrict__ a_dst2,
                              float* __restrict__ as2, float* __restrict__ ad2) {
    int gid = blockIdx.x * 256 + threadIdx.x;
    int n = gid >> 5, lane = gid & 31;
    if (n >= NN) return;
    float4 hv = *(const float4*)&h2[(size_t)n * DD + lane * 4];
    float4 sa = *(const float4*)&a_src2[lane * 4];
    float4 da = *(const float4*)&a_dst2[lane * 4];
    float s = hv.x * sa.x + hv.y * sa.y + hv.z * sa.z + hv.w * sa.w;
    float d = hv.x * da.x + hv.y * da.y + hv.z * da.z + hv.w * da.w;
#pragma unroll
    for (int o = 16; o > 0; o >>= 1) {
        s += __shfl_xor(s, o, 32);
        d += __shfl_xor(d, o, 32);
    }
    if (lane == 0) { as2[n] = s; ad2[n] = d; }
}

// ---- kernel 9: layer-2 segment max ------------------------------------------
__global__ void edge_max2(const int* __restrict__ ei,
                          const float* __restrict__ as2, const float* __restrict__ ad2,
                          float* __restrict__ m2) {
    int e = blockIdx.x * 256 + threadIdx.x;
    if (e >= ET) return;
    int s, d;
    if (e < NE) { s = ei[e]; d = ei[NE + e]; } else { s = e - NE; d = s; }
    float v = lrelu(as2[s] + ad2[d]);
    atomicMaxF(&m2[d], v);
}

// ---- kernel 10: layer-2 exp + denom + 128-dim h2 aggregation ----------------
__global__ void edge_sum2(const int* __restrict__ ei, const float* __restrict__ h2,
                          const float* __restrict__ as2, const float* __restrict__ ad2,
                          const float* __restrict__ m2,
                          float* __restrict__ den2, float* __restrict__ agg2) {
    int gid = blockIdx.x * 256 + threadIdx.x;
    int e = gid >> 5, lane = gid & 31;
    if (e >= ET) return;
    int s, d;
    if (e < NE) { s = ei[e]; d = ei[NE + e]; } else { s = e - NE; d = s; }
    float v = lrelu(as2[s] + ad2[d]);
    float ex = expf(v - m2[d]);
    if (lane == 0) atomicAdd(&den2[d], ex);
    float4 hv = *(const float4*)&h2[(size_t)s * DD + lane * 4];
    float* ag = &agg2[(size_t)d * DD + lane * 4];
    atomicAdd(ag + 0, ex * hv.x);
    atomicAdd(ag + 1, ex * hv.y);
    atomicAdd(ag + 2, ex * hv.z);
    atomicAdd(ag + 3, ex * hv.w);
}

// ---- kernel 11: x2 = elu(agg2/den2 + b2); pooled = segment_max(x2, batch) ---
__global__ void x2pool_kernel(const float* __restrict__ agg2, const float* __restrict__ den2,
                              const float* __restrict__ b2, const int* __restrict__ batch,
                              float* __restrict__ pooled) {
    int idx = blockIdx.x * 256 + threadIdx.x;   // NN*DD
    int n = idx >> 7, c = idx & 127;
    float v = agg2[idx] / (den2[n] + 1e-16f) + b2[c];
    v = eluf(v);
    atomicMaxF(&pooled[(size_t)batch[n] * DD + c], v);
}

// ---- kernel 12: out = relu(guard(pooled) @ Wfc + bfc) ------------------------
__global__ void final_kernel(const float* __restrict__ pooled, const float* __restrict__ Wfc,
                             const float* __restrict__ bfc, float* __restrict__ out) {
    int idx = blockIdx.x * 256 + threadIdx.x;   // NG*DD
    int g = idx >> 7, c = idx & 127;
    float acc = bfc[c];
#pragma unroll 8
    for (int k = 0; k < DD; ++k) {
        float p = pooled[g * DD + k];
        p = (p == -INFINITY) ? 0.f : p;
        acc = fmaf(p, Wfc[k * DD + c], acc);
    }
    out[idx] = acc > 0.f ? acc : 0.f;
}

extern "C" void kernel_launch(void* const* d_in, const int* in_sizes, int n_in,
                              void* d_out, int out_size, void* d_ws, size_t ws_size,
                              hipStream_t stream) {
    const float* x      = (const float*)d_in[0];
    const int*   ei     = (const int*)d_in[1];
    const int*   batch  = (const int*)d_in[3];
    const float* W1     = (const float*)d_in[4];
    const float* a_src1 = (const float*)d_in[5];
    const float* a_dst1 = (const float*)d_in[6];
    const float* b1     = (const float*)d_in[7];
    const float* W2     = (const float*)d_in[8];
    const float* a_src2 = (const float*)d_in[9];
    const float* a_dst2 = (const float*)d_in[10];
    const float* b2     = (const float*)d_in[11];
    const float* Wfc    = (const float*)d_in[12];
    const float* bfc    = (const float*)d_in[13];
    float* out = (float*)d_out;

    // workspace layout (floats) — total ~103 MB
    float* wsf   = (float*)d_ws;
    float* ws1   = wsf;                                  // 96
    float* wd1   = ws1 + 96;                             // 96
    float* as1   = wd1 + 96;                             // NN*H1
    float* ad1   = as1 + (size_t)NN * H1;                // NN*H1
    float* m1    = ad1 + (size_t)NN * H1;                // NN*H1
    float* den1  = m1  + (size_t)NN * H1;                // NN*H1
    float* xagg1 = den1 + (size_t)NN * H1;               // NN*H1*FIN
    float* h2    = xagg1 + (size_t)NN * H1 * FIN;        // NN*DD
    float* as2   = h2 + (size_t)NN * DD;                 // NN
    float* ad2   = as2 + NN;                             // NN
    float* m2    = ad2 + NN;                             // NN
    float* den2  = m2 + NN;                              // NN
    float* agg2  = den2 + NN;                            // NN*DD
    float* pooled= agg2 + (size_t)NN * DD;               // NG*DD

    prep_kernel  <<<1, 128, 0, stream>>>(W1, a_src1, a_dst1, ws1, wd1);
    alpha1_kernel<<<NN / 256, 256, 0, stream>>>(x, ws1, wd1, as1, ad1, m1, den1, xagg1, m2, den2);
    init2_kernel <<<(NN * DD + NG * DD + 255) / 256, 256, 0, stream>>>(agg2, pooled);
    edge_max1    <<<(ET * H1 + 255) / 256, 256, 0, stream>>>(ei, as1, ad1, m1);
    edge_sum1    <<<(ET * H1 + 255) / 256, 256, 0, stream>>>(ei, x, as1, ad1, m1, den1, xagg1);
    h2_gemm      <<<NN / 32, 256, 0, stream>>>(xagg1, den1, W1, b1, W2, h2);
    alpha2_kernel<<<(NN * 32) / 256, 256, 0, stream>>>(h2, a_src2, a_dst2, as2, ad2);
    edge_max2    <<<(ET + 255) / 256, 256, 0, stream>>>(ei, as2, ad2, m2);
    edge_sum2    <<<(ET * 32) / 256, 256, 0, stream>>>(ei, h2, as2, ad2, m2, den2, agg2);
    x2pool_kernel<<<(NN * DD) / 256, 256, 0, stream>>>(agg2, den2, b2, batch, pooled);
    final_kernel <<<(NG * DD) / 256, 256, 0, stream>>>(pooled, Wfc, bfc, out);
}

// Round 3
// 574.211 us; speedup vs baseline: 3.1764x; 3.1764x over previous
//
#include <hip/hip_runtime.h>
#include <hip/hip_bf16.h>
#include <math.h>

#define NN 65536          // nodes
#define NE 196608         // edges (without self loops)
#define ET (NE + NN)      // edges + self loops = 262144
#define NG 2048           // graphs
#define FIN 9
#define DD 128
#define H1 10
#define LRS 0.2f

__device__ __forceinline__ float lrelu(float v) { return v >= 0.f ? v : LRS * v; }
__device__ __forceinline__ float eluf(float v)  { return v > 0.f ? v : expm1f(v); }

// ---- kernel 1: fold W1 into per-head 9-dim logit vectors --------------------
__global__ void prep_kernel(const float* __restrict__ W1,
                            const float* __restrict__ a_src1,
                            const float* __restrict__ a_dst1,
                            float* __restrict__ ws1, float* __restrict__ wd1) {
    int t = threadIdx.x;
    if (t >= FIN * H1) return;
    int f = t / H1, h = t - f * H1;
    float s = 0.f, d = 0.f;
    for (int c = 0; c < DD; ++c) {
        float w = W1[f * (H1 * DD) + h * DD + c];
        s = fmaf(w, a_src1[h * DD + c], s);
        d = fmaf(w, a_dst1[h * DD + c], d);
    }
    ws1[t] = s;
    wd1[t] = d;
}

// ---- kernel 2: per-node attention logits + zero degree counters -------------
__global__ void alpha1_kernel(const float* __restrict__ x,
                              const float* __restrict__ ws1,
                              const float* __restrict__ wd1,
                              float* __restrict__ as1, float* __restrict__ ad1,
                              int* __restrict__ deg) {
    int n = blockIdx.x * 256 + threadIdx.x;
    if (n >= NN) return;
    float xv[FIN];
#pragma unroll
    for (int f = 0; f < FIN; ++f) xv[f] = x[(size_t)n * FIN + f];
#pragma unroll
    for (int h = 0; h < H1; ++h) {
        float s = 0.f, d = 0.f;
#pragma unroll
        for (int f = 0; f < FIN; ++f) {
            s = fmaf(xv[f], ws1[f * H1 + h], s);
            d = fmaf(xv[f], wd1[f * H1 + h], d);
        }
        as1[n * H1 + h] = s;
        ad1[n * H1 + h] = d;
    }
    deg[n] = 0;
}

// ---- CSR build: count / scan / scatter --------------------------------------
__global__ void count_kernel(const int* __restrict__ ei, int* __restrict__ deg) {
    int e = blockIdx.x * 256 + threadIdx.x;
    if (e >= ET) return;
    int d = (e < NE) ? ei[NE + e] : e - NE;
    atomicAdd(&deg[d], 1);
}

__global__ __launch_bounds__(1024) void scan_kernel(const int* __restrict__ deg,
                                                    int* __restrict__ rowptr,
                                                    int* __restrict__ cursor) {
    __shared__ int part[1024];
    int t = threadIdx.x;
    int sum = 0;
    for (int i = 0; i < 64; ++i) sum += deg[t * 64 + i];
    part[t] = sum;
    __syncthreads();
    for (int off = 1; off < 1024; off <<= 1) {
        int v = (t >= off) ? part[t - off] : 0;
        __syncthreads();
        part[t] += v;
        __syncthreads();
    }
    int run = (t == 0) ? 0 : part[t - 1];
    for (int i = 0; i < 64; ++i) {
        int idx = t * 64 + i;
        rowptr[idx] = run;
        cursor[idx] = run;
        run += deg[idx];
    }
    if (t == 1023) rowptr[NN] = run;
}

__global__ void scatter_kernel(const int* __restrict__ ei, int* __restrict__ cursor,
                               int* __restrict__ elist) {
    int e = blockIdx.x * 256 + threadIdx.x;
    if (e >= ET) return;
    int s, d;
    if (e < NE) { s = ei[e]; d = ei[NE + e]; } else { s = d = e - NE; }
    int pos = atomicAdd(&cursor[d], 1);
    elist[pos] = s;
}

// ---- per-graph node ranges from the sorted batch vector ---------------------
__global__ void gptr_kernel(const int* __restrict__ batch, int* __restrict__ gptr) {
    int n = blockIdx.x * 256 + threadIdx.x;
    if (n >= NN) return;
    int bn = batch[n];
    int bp = (n == 0) ? -1 : batch[n - 1];
    for (int g = bp + 1; g <= bn; ++g) gptr[g] = n;
    if (n == NN - 1) {
        for (int g = bn + 1; g <= NG; ++g) gptr[g] = NN;
    }
}

// ---- layer-1 aggregation: gather-side, registers only -----------------------
// one thread per (dst, head): max pass + accumulate pass; writes prenormalized
// 9-dim weighted-x aggregate (softmax fully applied).
__global__ void agg1_kernel(const int* __restrict__ rowptr, const int* __restrict__ elist,
                            const float* __restrict__ x,
                            const float* __restrict__ as1, const float* __restrict__ ad1,
                            float* __restrict__ xaggn) {
    int idx = blockIdx.x * 256 + threadIdx.x;     // NN*H1
    if (idx >= NN * H1) return;
    int d = idx / H1, h = idx - d * H1;
    int beg = rowptr[d], end = rowptr[d + 1];
    float adh = ad1[d * H1 + h];
    float m = -INFINITY;
    for (int j = beg; j < end; ++j) {
        float v = lrelu(as1[elist[j] * H1 + h] + adh);
        m = fmaxf(m, v);
    }
    float den = 0.f;
    float xa[FIN] = {};
    for (int j = beg; j < end; ++j) {
        int s = elist[j];
        float v = lrelu(as1[s * H1 + h] + adh);
        float ex = expf(v - m);
        den += ex;
        const float* xs = &x[(size_t)s * FIN];
#pragma unroll
        for (int f = 0; f < FIN; ++f) xa[f] = fmaf(ex, xs[f], xa[f]);
    }
    float inv = 1.f / (den + 1e-16f);
    float* o = &xaggn[(size_t)idx * FIN];
#pragma unroll
    for (int f = 0; f < FIN; ++f) o[f] = xa[f] * inv;
}

// ---- fused h2 = elu(xaggn@W1 + b1) @ W2 -------------------------------------
__global__ __launch_bounds__(256) void h2_gemm(const float* __restrict__ xaggn,
                                               const float* __restrict__ W1,
                                               const float* __restrict__ b1,
                                               const float* __restrict__ W2,
                                               float* __restrict__ h2) {
    __shared__ float Xs[32][65];
    const int n0 = blockIdx.x * 32;
    const int t = threadIdx.x;
    const int tx = t & 31, ty = t >> 5;
    const int jl = t & 63;
    const int rg = t >> 6;
    float acc[4][4] = {};
    for (int k0 = 0; k0 < H1 * DD; k0 += 64) {
        const int h = k0 >> 7;
        float w1c[FIN];
#pragma unroll
        for (int f = 0; f < FIN; ++f) w1c[f] = W1[f * (H1 * DD) + k0 + jl];
        const float b1j = b1[k0 + jl];
        __syncthreads();
#pragma unroll
        for (int r = 0; r < 8; ++r) {
            const int n = n0 + rg * 8 + r;
            const float* xa = &xaggn[((size_t)n * H1 + h) * FIN];
            float acc1 = b1j;
#pragma unroll
            for (int f = 0; f < FIN; ++f) acc1 = fmaf(xa[f], w1c[f], acc1);
            Xs[rg * 8 + r][jl] = eluf(acc1);
        }
        __syncthreads();
#pragma unroll 8
        for (int k = 0; k < 64; ++k) {
            float4 w = *(const float4*)&W2[(size_t)(k0 + k) * DD + tx * 4];
            float a0 = Xs[ty * 4 + 0][k];
            float a1 = Xs[ty * 4 + 1][k];
            float a2 = Xs[ty * 4 + 2][k];
            float a3 = Xs[ty * 4 + 3][k];
            acc[0][0] = fmaf(a0, w.x, acc[0][0]); acc[0][1] = fmaf(a0, w.y, acc[0][1]);
            acc[0][2] = fmaf(a0, w.z, acc[0][2]); acc[0][3] = fmaf(a0, w.w, acc[0][3]);
            acc[1][0] = fmaf(a1, w.x, acc[1][0]); acc[1][1] = fmaf(a1, w.y, acc[1][1]);
            acc[1][2] = fmaf(a1, w.z, acc[1][2]); acc[1][3] = fmaf(a1, w.w, acc[1][3]);
            acc[2][0] = fmaf(a2, w.x, acc[2][0]); acc[2][1] = fmaf(a2, w.y, acc[2][1]);
            acc[2][2] = fmaf(a2, w.z, acc[2][2]); acc[2][3] = fmaf(a2, w.w, acc[2][3]);
            acc[3][0] = fmaf(a3, w.x, acc[3][0]); acc[3][1] = fmaf(a3, w.y, acc[3][1]);
            acc[3][2] = fmaf(a3, w.z, acc[3][2]); acc[3][3] = fmaf(a3, w.w, acc[3][3]);
        }
    }
#pragma unroll
    for (int r = 0; r < 4; ++r) {
        float4 v = make_float4(acc[r][0], acc[r][1], acc[r][2], acc[r][3]);
        *(float4*)&h2[(size_t)(n0 + ty * 4 + r) * DD + tx * 4] = v;
    }
}

// ---- layer-2 logits (32 lanes per node, shuffle reduce) ---------------------
__global__ void alpha2_kernel(const float* __restrict__ h2,
                              const float* __restrict__ a_src2,
                              const float* __restrict__ a_dst2,
                              float* __restrict__ as2, float* __restrict__ ad2) {
    int gid = blockIdx.x * 256 + threadIdx.x;
    int n = gid >> 5, lane = gid & 31;
    if (n >= NN) return;
    float4 hv = *(const float4*)&h2[(size_t)n * DD + lane * 4];
    float4 sa = *(const float4*)&a_src2[lane * 4];
    float4 da = *(const float4*)&a_dst2[lane * 4];
    float s = hv.x * sa.x + hv.y * sa.y + hv.z * sa.z + hv.w * sa.w;
    float d = hv.x * da.x + hv.y * da.y + hv.z * da.z + hv.w * da.w;
#pragma unroll
    for (int o = 16; o > 0; o >>= 1) {
        s += __shfl_xor(s, o, 32);
        d += __shfl_xor(d, o, 32);
    }
    if (lane == 0) { as2[n] = s; ad2[n] = d; }
}

// ---- layer-2 aggregation: gather-side, 32 lanes per dst node ----------------
// writes x2 = elu(softmax-weighted h2 + b2) directly.
__global__ void agg2_kernel(const int* __restrict__ rowptr, const int* __restrict__ elist,
                            const float* __restrict__ h2,
                            const float* __restrict__ as2, const float* __restrict__ ad2,
                            const float* __restrict__ b2, float* __restrict__ x2) {
    int gid = blockIdx.x * 256 + threadIdx.x;
    int n = gid >> 5, lane = gid & 31;
    if (n >= NN) return;
    int beg = rowptr[n], end = rowptr[n + 1];
    float adn = ad2[n];
    float m = -INFINITY;
    for (int j = beg; j < end; ++j)
        m = fmaxf(m, lrelu(as2[elist[j]] + adn));
    float den = 0.f;
    float4 acc = make_float4(0.f, 0.f, 0.f, 0.f);
    for (int j = beg; j < end; ++j) {
        int s = elist[j];
        float ex = expf(lrelu(as2[s] + adn) - m);
        den += ex;
        float4 hv = *(const float4*)&h2[(size_t)s * DD + lane * 4];
        acc.x = fmaf(ex, hv.x, acc.x);
        acc.y = fmaf(ex, hv.y, acc.y);
        acc.z = fmaf(ex, hv.z, acc.z);
        acc.w = fmaf(ex, hv.w, acc.w);
    }
    float inv = 1.f / (den + 1e-16f);
    float4 bv = *(const float4*)&b2[lane * 4];
    float4 r;
    r.x = eluf(acc.x * inv + bv.x);
    r.y = eluf(acc.y * inv + bv.y);
    r.z = eluf(acc.z * inv + bv.z);
    r.w = eluf(acc.w * inv + bv.w);
    *(float4*)&x2[(size_t)n * DD + lane * 4] = r;
}

// ---- pooling: one block per graph over its contiguous node range ------------
__global__ void pool_kernel(const int* __restrict__ gptr, const float* __restrict__ x2,
                            float* __restrict__ pooled) {
    int g = blockIdx.x;
    int c = threadIdx.x;          // 128 channels
    int beg = gptr[g], end = gptr[g + 1];
    float v = -INFINITY;
    for (int n = beg; n < end; ++n)
        v = fmaxf(v, x2[(size_t)n * DD + c]);
    if (beg == end) v = 0.f;      // empty graph -> 0 (isfinite guard)
    pooled[g * DD + c] = v;
}

// ---- out = relu(pooled @ Wfc + bfc) -----------------------------------------
__global__ void final_kernel(const float* __restrict__ pooled, const float* __restrict__ Wfc,
                             const float* __restrict__ bfc, float* __restrict__ out) {
    int idx = blockIdx.x * 256 + threadIdx.x;   // NG*DD
    int g = idx >> 7, c = idx & 127;
    float acc = bfc[c];
#pragma unroll 8
    for (int k = 0; k < DD; ++k)
        acc = fmaf(pooled[g * DD + k], Wfc[k * DD + c], acc);
    out[idx] = acc > 0.f ? acc : 0.f;
}

extern "C" void kernel_launch(void* const* d_in, const int* in_sizes, int n_in,
                              void* d_out, int out_size, void* d_ws, size_t ws_size,
                              hipStream_t stream) {
    const float* x      = (const float*)d_in[0];
    const int*   ei     = (const int*)d_in[1];
    const int*   batch  = (const int*)d_in[3];
    const float* W1     = (const float*)d_in[4];
    const float* a_src1 = (const float*)d_in[5];
    const float* a_dst1 = (const float*)d_in[6];
    const float* b1     = (const float*)d_in[7];
    const float* W2     = (const float*)d_in[8];
    const float* a_src2 = (const float*)d_in[9];
    const float* a_dst2 = (const float*)d_in[10];
    const float* b2     = (const float*)d_in[11];
    const float* Wfc    = (const float*)d_in[12];
    const float* bfc    = (const float*)d_in[13];
    float* out = (float*)d_out;

    // workspace layout — ~97 MB total
    float* wsf    = (float*)d_ws;
    float* ws1    = wsf;                                   // 96
    float* wd1    = ws1 + 96;                              // 96
    float* as1    = wd1 + 96;                              // NN*H1
    float* ad1    = as1 + (size_t)NN * H1;                 // NN*H1
    float* xaggn  = ad1 + (size_t)NN * H1;                 // NN*H1*FIN
    float* h2     = xaggn + (size_t)NN * H1 * FIN;         // NN*DD
    float* as2    = h2 + (size_t)NN * DD;                  // NN
    float* ad2    = as2 + NN;                              // NN
    float* x2     = ad2 + NN;                              // NN*DD
    float* pooled = x2 + (size_t)NN * DD;                  // NG*DD
    int*   deg    = (int*)(pooled + (size_t)NG * DD);      // NN
    int*   rowptr = deg + NN;                              // NN+1
    int*   cursor = rowptr + NN + 1;                       // NN
    int*   elist  = cursor + NN;                           // ET
    int*   gptr   = elist + ET;                            // NG+1

    prep_kernel   <<<1, 128, 0, stream>>>(W1, a_src1, a_dst1, ws1, wd1);
    alpha1_kernel <<<NN / 256, 256, 0, stream>>>(x, ws1, wd1, as1, ad1, deg);
    count_kernel  <<<(ET + 255) / 256, 256, 0, stream>>>(ei, deg);
    scan_kernel   <<<1, 1024, 0, stream>>>(deg, rowptr, cursor);
    scatter_kernel<<<(ET + 255) / 256, 256, 0, stream>>>(ei, cursor, elist);
    gptr_kernel   <<<NN / 256, 256, 0, stream>>>(batch, gptr);
    agg1_kernel   <<<(NN * H1 + 255) / 256, 256, 0, stream>>>(rowptr, elist, x, as1, ad1, xaggn);
    h2_gemm       <<<NN / 32, 256, 0, stream>>>(xaggn, W1, b1, W2, h2);
    alpha2_kernel <<<(NN * 32) / 256, 256, 0, stream>>>(h2, a_src2, a_dst2, as2, ad2);
    agg2_kernel   <<<(NN * 32) / 256, 256, 0, stream>>>(rowptr, elist, h2, as2, ad2, b2, x2);
    pool_kernel   <<<NG, 128, 0, stream>>>(gptr, x2, pooled);
    final_kernel  <<<(NG * DD) / 256, 256, 0, stream>>>(pooled, Wfc, bfc, out);
}

// Round 4
// 312.318 us; speedup vs baseline: 5.8399x; 1.8385x over previous
//
#include <hip/hip_runtime.h>
#include <hip/hip_bf16.h>
#include <math.h>

#define NN 65536          // nodes
#define NE 196608         // edges (without self loops)
#define ET (NE + NN)      // edges + self loops = 262144
#define NG 2048           // graphs
#define FIN 9
#define DD 128
#define H1 10
#define KK (H1 * DD)      // 1280
#define LRS 0.2f

typedef __attribute__((ext_vector_type(8))) short short8v;
typedef __attribute__((ext_vector_type(4))) float f32x4;

__device__ __forceinline__ float lrelu(float v) { return v >= 0.f ? v : LRS * v; }
__device__ __forceinline__ float eluf(float v)  { return v > 0.f ? v : expm1f(v); }

// float -> bf16 round-to-nearest-even (3 int ops, no libcall)
__device__ __forceinline__ unsigned short f2bf(float f) {
    unsigned int u = __float_as_uint(f);
    u += 0x7FFFu + ((u >> 16) & 1u);
    return (unsigned short)(u >> 16);
}

// ---- kernel 1: fold W1 into per-head 9-dim logit vectors --------------------
__global__ void prep_kernel(const float* __restrict__ W1,
                            const float* __restrict__ a_src1,
                            const float* __restrict__ a_dst1,
                            float* __restrict__ ws1, float* __restrict__ wd1) {
    int t = threadIdx.x;
    if (t >= FIN * H1) return;
    int f = t / H1, h = t - f * H1;
    float s = 0.f, d = 0.f;
    for (int c = 0; c < DD; ++c) {
        float w = W1[f * KK + h * DD + c];
        s = fmaf(w, a_src1[h * DD + c], s);
        d = fmaf(w, a_dst1[h * DD + c], d);
    }
    ws1[t] = s;
    wd1[t] = d;
}

// ---- pack W2 (1280x128 fp32) into bf16 B-fragment layout --------------------
// W2p[((kt*8 + nt)*64 + lane)*8 + r] = bf16(W2[kt*32 + (lane>>4)*8 + r][nt*16 + (lane&15)])
__global__ void packW2_kernel(const float* __restrict__ W2, unsigned short* __restrict__ W2p) {
    int idx = blockIdx.x * 256 + threadIdx.x;
    if (idx >= KK * DD) return;
    int r  = idx & 7;
    int l  = (idx >> 3) & 63;
    int nt = (idx >> 9) & 7;
    int kt = idx >> 12;
    int k = kt * 32 + ((l >> 4) << 3) + r;
    int n = nt * 16 + (l & 15);
    W2p[idx] = f2bf(W2[(size_t)k * DD + n]);
}

// ---- kernel 2: per-node attention logits + zero degree counters -------------
__global__ void alpha1_kernel(const float* __restrict__ x,
                              const float* __restrict__ ws1,
                              const float* __restrict__ wd1,
                              float* __restrict__ as1, float* __restrict__ ad1,
                              int* __restrict__ deg) {
    int n = blockIdx.x * 256 + threadIdx.x;
    if (n >= NN) return;
    float xv[FIN];
#pragma unroll
    for (int f = 0; f < FIN; ++f) xv[f] = x[(size_t)n * FIN + f];
#pragma unroll
    for (int h = 0; h < H1; ++h) {
        float s = 0.f, d = 0.f;
#pragma unroll
        for (int f = 0; f < FIN; ++f) {
            s = fmaf(xv[f], ws1[f * H1 + h], s);
            d = fmaf(xv[f], wd1[f * H1 + h], d);
        }
        as1[n * H1 + h] = s;
        ad1[n * H1 + h] = d;
    }
    deg[n] = 0;
}

// ---- CSR build: count / scan / scatter --------------------------------------
__global__ void count_kernel(const int* __restrict__ ei, int* __restrict__ deg) {
    int e = blockIdx.x * 256 + threadIdx.x;
    if (e >= ET) return;
    int d = (e < NE) ? ei[NE + e] : e - NE;
    atomicAdd(&deg[d], 1);
}

__global__ __launch_bounds__(1024) void scan_kernel(const int* __restrict__ deg,
                                                    int* __restrict__ rowptr,
                                                    int* __restrict__ cursor) {
    __shared__ int part[1024];
    int t = threadIdx.x;
    int sum = 0;
    for (int i = 0; i < 64; ++i) sum += deg[t * 64 + i];
    part[t] = sum;
    __syncthreads();
    for (int off = 1; off < 1024; off <<= 1) {
        int v = (t >= off) ? part[t - off] : 0;
        __syncthreads();
        part[t] += v;
        __syncthreads();
    }
    int run = (t == 0) ? 0 : part[t - 1];
    for (int i = 0; i < 64; ++i) {
        int idx = t * 64 + i;
        rowptr[idx] = run;
        cursor[idx] = run;
        run += deg[idx];
    }
    if (t == 1023) rowptr[NN] = run;
}

__global__ void scatter_kernel(const int* __restrict__ ei, int* __restrict__ cursor,
                               int* __restrict__ elist) {
    int e = blockIdx.x * 256 + threadIdx.x;
    if (e >= ET) return;
    int s, d;
    if (e < NE) { s = ei[e]; d = ei[NE + e]; } else { s = d = e - NE; }
    int pos = atomicAdd(&cursor[d], 1);
    elist[pos] = s;
}

// ---- per-graph node ranges from the sorted batch vector ---------------------
__global__ void gptr_kernel(const int* __restrict__ batch, int* __restrict__ gptr) {
    int n = blockIdx.x * 256 + threadIdx.x;
    if (n >= NN) return;
    int bn = batch[n];
    int bp = (n == 0) ? -1 : batch[n - 1];
    for (int g = bp + 1; g <= bn; ++g) gptr[g] = n;
    if (n == NN - 1) {
        for (int g = bn + 1; g <= NG; ++g) gptr[g] = NN;
    }
}

// ---- layer-1 aggregation: gather-side, registers only -----------------------
__global__ void agg1_kernel(const int* __restrict__ rowptr, const int* __restrict__ elist,
                            const float* __restrict__ x,
                            const float* __restrict__ as1, const float* __restrict__ ad1,
                            float* __restrict__ xaggn) {
    int idx = blockIdx.x * 256 + threadIdx.x;     // NN*H1
    if (idx >= NN * H1) return;
    int d = idx / H1, h = idx - d * H1;
    int beg = rowptr[d], end = rowptr[d + 1];
    float adh = ad1[d * H1 + h];
    float m = -INFINITY;
    for (int j = beg; j < end; ++j) {
        float v = lrelu(as1[elist[j] * H1 + h] + adh);
        m = fmaxf(m, v);
    }
    float den = 0.f;
    float xa[FIN] = {};
    for (int j = beg; j < end; ++j) {
        int s = elist[j];
        float v = lrelu(as1[s * H1 + h] + adh);
        float ex = expf(v - m);
        den += ex;
        const float* xs = &x[(size_t)s * FIN];
#pragma unroll
        for (int f = 0; f < FIN; ++f) xa[f] = fmaf(ex, xs[f], xa[f]);
    }
    float inv = 1.f / (den + 1e-16f);
    float* o = &xaggn[(size_t)idx * FIN];
#pragma unroll
    for (int f = 0; f < FIN; ++f) o[f] = xa[f] * inv;
}

// ---- fused h2 = elu(xaggn@W1 + b1) @ W2  via MFMA ---------------------------
// Block: 64 rows x 128 cols. x1 tile (64x64) built on the fly into LDS (bf16,
// XOR-swizzled at 16B granules). 4 waves tile N (32 cols each). B from W2p
// (pre-packed bf16 fragments, L2-resident).
__global__ __launch_bounds__(256) void h2_gemm(const float* __restrict__ xaggn,
                                               const float* __restrict__ W1,
                                               const float* __restrict__ b1,
                                               const unsigned short* __restrict__ W2p,
                                               float* __restrict__ h2) {
    __shared__ unsigned short Xs[64 * 64];        // 8 KB
    const int n0 = blockIdx.x * 64;
    const int t = threadIdx.x;
    const int jl = t & 63;                        // build: k column within tile
    const int wv = t >> 6;                        // wave id == build row group
    const int lane = t & 63;
    const int rlo = lane & 15, khi = lane >> 4;
    const int gkw = jl >> 3, giw = jl & 7;        // build: granule / slot

    f32x4 acc[4][2];
#pragma unroll
    for (int mt = 0; mt < 4; ++mt)
#pragma unroll
        for (int ntl = 0; ntl < 2; ++ntl)
#pragma unroll
            for (int q = 0; q < 4; ++q) acc[mt][ntl][q] = 0.f;

    for (int k0 = 0; k0 < KK; k0 += 64) {
        const int h = k0 >> 7;                    // head (128 | k0-range of 64)
        float w1c[FIN];
#pragma unroll
        for (int f = 0; f < FIN; ++f) w1c[f] = W1[f * KK + k0 + jl];
        const float b1j = b1[k0 + jl];
        __syncthreads();                          // prev-iter LDS reads done
#pragma unroll
        for (int r = 0; r < 16; ++r) {
            const int row = wv * 16 + r;
            const float* xa = &xaggn[((size_t)(n0 + row) * H1 + h) * FIN];
            float a1 = b1j;
#pragma unroll
            for (int f = 0; f < FIN; ++f) a1 = fmaf(xa[f], w1c[f], a1);
            a1 = a1 > 0.f ? a1 : __expf(a1) - 1.f;   // fast ELU
            Xs[row * 64 + ((gkw ^ (row & 7)) << 3) + giw] = f2bf(a1);
        }
        __syncthreads();
#pragma unroll
        for (int ks = 0; ks < 2; ++ks) {
            const int ktabs = (k0 >> 5) + ks;
            short8v bfr[2];
#pragma unroll
            for (int ntl = 0; ntl < 2; ++ntl) {
                const int nt = wv * 2 + ntl;
                bfr[ntl] = *(const short8v*)&W2p[(((size_t)ktabs * 8 + nt) * 64 + lane) * 8];
            }
#pragma unroll
            for (int mt = 0; mt < 4; ++mt) {
                const int row = mt * 16 + rlo;
                const int gk = ks * 4 + khi;
                short8v af = *(const short8v*)&Xs[row * 64 + ((gk ^ (row & 7)) << 3)];
                acc[mt][0] = __builtin_amdgcn_mfma_f32_16x16x32_bf16(af, bfr[0], acc[mt][0], 0, 0, 0);
                acc[mt][1] = __builtin_amdgcn_mfma_f32_16x16x32_bf16(af, bfr[1], acc[mt][1], 0, 0, 0);
            }
        }
    }
    // C write: col = lane&15, row = (lane>>4)*4 + reg   (m89-verified layout)
#pragma unroll
    for (int mt = 0; mt < 4; ++mt)
#pragma unroll
        for (int ntl = 0; ntl < 2; ++ntl)
#pragma unroll
            for (int q = 0; q < 4; ++q) {
                int row = n0 + mt * 16 + khi * 4 + q;
                int col = wv * 32 + ntl * 16 + rlo;
                h2[(size_t)row * DD + col] = acc[mt][ntl][q];
            }
}

// ---- layer-2 logits (32 lanes per node, shuffle reduce) ---------------------
__global__ void alpha2_kernel(const float* __restrict__ h2,
                              const float* __restrict__ a_src2,
                              const float* __restrict__ a_dst2,
                              float* __restrict__ as2, float* __restrict__ ad2) {
    int gid = blockIdx.x * 256 + threadIdx.x;
    int n = gid >> 5, lane = gid & 31;
    if (n >= NN) return;
    float4 hv = *(const float4*)&h2[(size_t)n * DD + lane * 4];
    float4 sa = *(const float4*)&a_src2[lane * 4];
    float4 da = *(const float4*)&a_dst2[lane * 4];
    float s = hv.x * sa.x + hv.y * sa.y + hv.z * sa.z + hv.w * sa.w;
    float d = hv.x * da.x + hv.y * da.y + hv.z * da.z + hv.w * da.w;
#pragma unroll
    for (int o = 16; o > 0; o >>= 1) {
        s += __shfl_xor(s, o, 32);
        d += __shfl_xor(d, o, 32);
    }
    if (lane == 0) { as2[n] = s; ad2[n] = d; }
}

// ---- layer-2 aggregation: gather-side, 32 lanes per dst node ----------------
__global__ void agg2_kernel(const int* __restrict__ rowptr, const int* __restrict__ elist,
                            const float* __restrict__ h2,
                            const float* __restrict__ as2, const float* __restrict__ ad2,
                            const float* __restrict__ b2, float* __restrict__ x2) {
    int gid = blockIdx.x * 256 + threadIdx.x;
    int n = gid >> 5, lane = gid & 31;
    if (n >= NN) return;
    int beg = rowptr[n], end = rowptr[n + 1];
    float adn = ad2[n];
    float m = -INFINITY;
    for (int j = beg; j < end; ++j)
        m = fmaxf(m, lrelu(as2[elist[j]] + adn));
    float den = 0.f;
    float4 acc = make_float4(0.f, 0.f, 0.f, 0.f);
    for (int j = beg; j < end; ++j) {
        int s = elist[j];
        float ex = expf(lrelu(as2[s] + adn) - m);
        den += ex;
        float4 hv = *(const float4*)&h2[(size_t)s * DD + lane * 4];
        acc.x = fmaf(ex, hv.x, acc.x);
        acc.y = fmaf(ex, hv.y, acc.y);
        acc.z = fmaf(ex, hv.z, acc.z);
        acc.w = fmaf(ex, hv.w, acc.w);
    }
    float inv = 1.f / (den + 1e-16f);
    float4 bv = *(const float4*)&b2[lane * 4];
    float4 r;
    r.x = eluf(acc.x * inv + bv.x);
    r.y = eluf(acc.y * inv + bv.y);
    r.z = eluf(acc.z * inv + bv.z);
    r.w = eluf(acc.w * inv + bv.w);
    *(float4*)&x2[(size_t)n * DD + lane * 4] = r;
}

// ---- pooling: one block per graph over its contiguous node range ------------
__global__ void pool_kernel(const int* __restrict__ gptr, const float* __restrict__ x2,
                            float* __restrict__ pooled) {
    int g = blockIdx.x;
    int c = threadIdx.x;          // 128 channels
    int beg = gptr[g], end = gptr[g + 1];
    float v = -INFINITY;
    for (int n = beg; n < end; ++n)
        v = fmaxf(v, x2[(size_t)n * DD + c]);
    if (beg == end) v = 0.f;      // empty graph -> 0 (isfinite guard)
    pooled[g * DD + c] = v;
}

// ---- out = relu(pooled @ Wfc + bfc) -----------------------------------------
__global__ void final_kernel(const float* __restrict__ pooled, const float* __restrict__ Wfc,
                             const float* __restrict__ bfc, float* __restrict__ out) {
    int idx = blockIdx.x * 256 + threadIdx.x;   // NG*DD
    int g = idx >> 7, c = idx & 127;
    float acc = bfc[c];
#pragma unroll 8
    for (int k = 0; k < DD; ++k)
        acc = fmaf(pooled[g * DD + k], Wfc[k * DD + c], acc);
    out[idx] = acc > 0.f ? acc : 0.f;
}

extern "C" void kernel_launch(void* const* d_in, const int* in_sizes, int n_in,
                              void* d_out, int out_size, void* d_ws, size_t ws_size,
                              hipStream_t stream) {
    const float* x      = (const float*)d_in[0];
    const int*   ei     = (const int*)d_in[1];
    const int*   batch  = (const int*)d_in[3];
    const float* W1     = (const float*)d_in[4];
    const float* a_src1 = (const float*)d_in[5];
    const float* a_dst1 = (const float*)d_in[6];
    const float* b1     = (const float*)d_in[7];
    const float* W2     = (const float*)d_in[8];
    const float* a_src2 = (const float*)d_in[9];
    const float* a_dst2 = (const float*)d_in[10];
    const float* b2     = (const float*)d_in[11];
    const float* Wfc    = (const float*)d_in[12];
    const float* bfc    = (const float*)d_in[13];
    float* out = (float*)d_out;

    // workspace layout — ~98 MB total
    float* wsf    = (float*)d_ws;
    float* ws1    = wsf;                                   // 96
    float* wd1    = ws1 + 96;                              // 96
    float* as1    = wd1 + 96;                              // NN*H1
    float* ad1    = as1 + (size_t)NN * H1;                 // NN*H1
    float* xaggn  = ad1 + (size_t)NN * H1;                 // NN*H1*FIN
    float* h2     = xaggn + (size_t)NN * H1 * FIN;         // NN*DD
    float* as2    = h2 + (size_t)NN * DD;                  // NN
    float* ad2    = as2 + NN;                              // NN
    float* x2     = ad2 + NN;                              // NN*DD
    float* pooled = x2 + (size_t)NN * DD;                  // NG*DD
    int*   deg    = (int*)(pooled + (size_t)NG * DD);      // NN
    int*   rowptr = deg + NN;                              // NN+1
    int*   cursor = rowptr + NN + 1;                       // NN
    int*   elist  = cursor + NN;                           // ET
    int*   gptr   = elist + ET;                            // NG+1
    // align W2p to 16 bytes
    size_t off = (size_t)((char*)(gptr + NG + 1) - (char*)d_ws);
    off = (off + 15) & ~(size_t)15;
    unsigned short* W2p = (unsigned short*)((char*)d_ws + off);  // KK*DD bf16

    prep_kernel   <<<1, 128, 0, stream>>>(W1, a_src1, a_dst1, ws1, wd1);
    packW2_kernel <<<(KK * DD + 255) / 256, 256, 0, stream>>>(W2, W2p);
    alpha1_kernel <<<NN / 256, 256, 0, stream>>>(x, ws1, wd1, as1, ad1, deg);
    count_kernel  <<<(ET + 255) / 256, 256, 0, stream>>>(ei, deg);
    scan_kernel   <<<1, 1024, 0, stream>>>(deg, rowptr, cursor);
    scatter_kernel<<<(ET + 255) / 256, 256, 0, stream>>>(ei, cursor, elist);
    gptr_kernel   <<<NN / 256, 256, 0, stream>>>(batch, gptr);
    agg1_kernel   <<<(NN * H1 + 255) / 256, 256, 0, stream>>>(rowptr, elist, x, as1, ad1, xaggn);
    h2_gemm       <<<NN / 64, 256, 0, stream>>>(xaggn, W1, b1, W2p, h2);
    alpha2_kernel <<<(NN * 32) / 256, 256, 0, stream>>>(h2, a_src2, a_dst2, as2, ad2);
    agg2_kernel   <<<(NN * 32) / 256, 256, 0, stream>>>(rowptr, elist, h2, as2, ad2, b2, x2);
    pool_kernel   <<<NG, 128, 0, stream>>>(gptr, x2, pooled);
    final_kernel  <<<(NG * DD) / 256, 256, 0, stream>>>(pooled, Wfc, bfc, out);
}

// Round 5
// 234.508 us; speedup vs baseline: 7.7777x; 1.3318x over previous
//
#include <hip/hip_runtime.h>
#include <hip/hip_bf16.h>
#include <math.h>

#define NN 65536          // nodes
#define NE 196608         // edges (without self loops)
#define ET (NE + NN)      // edges + self loops = 262144
#define NG 2048           // graphs
#define FIN 9
#define DD 128
#define H1 10
#define KK (H1 * DD)      // 1280
#define LRS 0.2f

typedef __attribute__((ext_vector_type(8))) short short8v;
typedef __attribute__((ext_vector_type(4))) float f32x4;

__device__ __forceinline__ float lrelu(float v) { return v >= 0.f ? v : LRS * v; }
__device__ __forceinline__ float eluf(float v)  { return v > 0.f ? v : expm1f(v); }

// float -> bf16 round-to-nearest-even (3 int ops, no libcall)
__device__ __forceinline__ unsigned short f2bf(float f) {
    unsigned int u = __float_as_uint(f);
    u += 0x7FFFu + ((u >> 16) & 1u);
    return (unsigned short)(u >> 16);
}

// ---- kernel 1: fold W1 into per-head 9-dim logit vectors --------------------
__global__ void prep_kernel(const float* __restrict__ W1,
                            const float* __restrict__ a_src1,
                            const float* __restrict__ a_dst1,
                            float* __restrict__ ws1, float* __restrict__ wd1) {
    int t = threadIdx.x;
    if (t >= FIN * H1) return;
    int f = t / H1, h = t - f * H1;
    float s = 0.f, d = 0.f;
    for (int c = 0; c < DD; ++c) {
        float w = W1[f * KK + h * DD + c];
        s = fmaf(w, a_src1[h * DD + c], s);
        d = fmaf(w, a_dst1[h * DD + c], d);
    }
    ws1[t] = s;
    wd1[t] = d;
}

// ---- pack W2 (1280x128 fp32) into bf16 B-fragment layout --------------------
// W2p[((kt*8 + nt)*64 + lane)*8 + r] = bf16(W2[kt*32 + (lane>>4)*8 + r][nt*16 + (lane&15)])
__global__ void packW2_kernel(const float* __restrict__ W2, unsigned short* __restrict__ W2p) {
    int idx = blockIdx.x * 256 + threadIdx.x;
    if (idx >= KK * DD) return;
    int r  = idx & 7;
    int l  = (idx >> 3) & 63;
    int nt = (idx >> 9) & 7;
    int kt = idx >> 12;
    int k = kt * 32 + ((l >> 4) << 3) + r;
    int n = nt * 16 + (l & 15);
    W2p[idx] = f2bf(W2[(size_t)k * DD + n]);
}

// ---- kernel 2: per-node attention logits + zero degree counters -------------
__global__ void alpha1_kernel(const float* __restrict__ x,
                              const float* __restrict__ ws1,
                              const float* __restrict__ wd1,
                              float* __restrict__ as1, float* __restrict__ ad1,
                              int* __restrict__ deg) {
    int n = blockIdx.x * 256 + threadIdx.x;
    if (n >= NN) return;
    float xv[FIN];
#pragma unroll
    for (int f = 0; f < FIN; ++f) xv[f] = x[(size_t)n * FIN + f];
#pragma unroll
    for (int h = 0; h < H1; ++h) {
        float s = 0.f, d = 0.f;
#pragma unroll
        for (int f = 0; f < FIN; ++f) {
            s = fmaf(xv[f], ws1[f * H1 + h], s);
            d = fmaf(xv[f], wd1[f * H1 + h], d);
        }
        as1[n * H1 + h] = s;
        ad1[n * H1 + h] = d;
    }
    deg[n] = 0;
}

// ---- CSR build: count / scan / scatter --------------------------------------
__global__ void count_kernel(const int* __restrict__ ei, int* __restrict__ deg) {
    int e = blockIdx.x * 256 + threadIdx.x;
    if (e >= ET) return;
    int d = (e < NE) ? ei[NE + e] : e - NE;
    atomicAdd(&deg[d], 1);
}

__global__ __launch_bounds__(1024) void scan_kernel(const int* __restrict__ deg,
                                                    int* __restrict__ rowptr,
                                                    int* __restrict__ cursor) {
    __shared__ int part[1024];
    int t = threadIdx.x;
    int sum = 0;
    for (int i = 0; i < 64; ++i) sum += deg[t * 64 + i];
    part[t] = sum;
    __syncthreads();
    for (int off = 1; off < 1024; off <<= 1) {
        int v = (t >= off) ? part[t - off] : 0;
        __syncthreads();
        part[t] += v;
        __syncthreads();
    }
    int run = (t == 0) ? 0 : part[t - 1];
    for (int i = 0; i < 64; ++i) {
        int idx = t * 64 + i;
        rowptr[idx] = run;
        cursor[idx] = run;
        run += deg[idx];
    }
    if (t == 1023) rowptr[NN] = run;
}

__global__ void scatter_kernel(const int* __restrict__ ei, int* __restrict__ cursor,
                               int* __restrict__ elist) {
    int e = blockIdx.x * 256 + threadIdx.x;
    if (e >= ET) return;
    int s, d;
    if (e < NE) { s = ei[e]; d = ei[NE + e]; } else { s = d = e - NE; }
    int pos = atomicAdd(&cursor[d], 1);
    elist[pos] = s;
}

// ---- per-graph node ranges from the sorted batch vector ---------------------
__global__ void gptr_kernel(const int* __restrict__ batch, int* __restrict__ gptr) {
    int n = blockIdx.x * 256 + threadIdx.x;
    if (n >= NN) return;
    int bn = batch[n];
    int bp = (n == 0) ? -1 : batch[n - 1];
    for (int g = bp + 1; g <= bn; ++g) gptr[g] = n;
    if (n == NN - 1) {
        for (int g = bn + 1; g <= NG; ++g) gptr[g] = NN;
    }
}

// ---- layer-1 aggregation: gather-side, registers only -----------------------
__global__ void agg1_kernel(const int* __restrict__ rowptr, const int* __restrict__ elist,
                            const float* __restrict__ x,
                            const float* __restrict__ as1, const float* __restrict__ ad1,
                            float* __restrict__ xaggn) {
    int idx = blockIdx.x * 256 + threadIdx.x;     // NN*H1
    if (idx >= NN * H1) return;
    int d = idx / H1, h = idx - d * H1;
    int beg = rowptr[d], end = rowptr[d + 1];
    float adh = ad1[d * H1 + h];
    float m = -INFINITY;
    for (int j = beg; j < end; ++j) {
        float v = lrelu(as1[elist[j] * H1 + h] + adh);
        m = fmaxf(m, v);
    }
    float den = 0.f;
    float xa[FIN] = {};
    for (int j = beg; j < end; ++j) {
        int s = elist[j];
        float v = lrelu(as1[s * H1 + h] + adh);
        float ex = expf(v - m);
        den += ex;
        const float* xs = &x[(size_t)s * FIN];
#pragma unroll
        for (int f = 0; f < FIN; ++f) xa[f] = fmaf(ex, xs[f], xa[f]);
    }
    float inv = 1.f / (den + 1e-16f);
    float* o = &xaggn[(size_t)idx * FIN];
#pragma unroll
    for (int f = 0; f < FIN; ++f) o[f] = xa[f] * inv;
}

// ---- fused h2 = elu(xaggn@W1 + b1) @ W2  via MFMA ---------------------------
// Block: 64 rows x 128 cols, 4 waves. xagg staged in LDS once (stride-97 pad);
// x1 tile built per K-step by row-resident threads: xa in VGPRs, W1 columns
// wave-uniform -> scalar loads (SMEM). Main loop reads Xs via XOR-swizzled
// ds_read_b128 + mfma_f32_16x16x32_bf16 against prepacked W2p fragments.
__global__ __launch_bounds__(256) void h2_gemm(const float* __restrict__ xaggn,
                                               const float* __restrict__ W1,
                                               const float* __restrict__ b1,
                                               const unsigned short* __restrict__ W2p,
                                               float* __restrict__ h2) {
    __shared__ float xagg_s[64 * 97];             // 24.8 KB (stride 97: bank = row mod 32)
    __shared__ unsigned short Xs[64 * 64];        // 8 KB, XOR-swizzled 16B granules
    const int t = threadIdx.x;
    const int n0 = blockIdx.x * 64;

    // stage xagg block (coalesced read, conflict-free LDS write)
    for (int idx = t; idx < 64 * 90; idx += 256) {
        int row = idx / 90, c = idx - row * 90;
        xagg_s[row * 97 + c] = xaggn[(size_t)n0 * 90 + idx];
        (void)row; (void)c;
    }

    const int row = t & 63;                                        // build row
    const int wvu = __builtin_amdgcn_readfirstlane(t >> 6);        // wave id (SGPR)
    const int lane = t & 63;
    const int rlo = lane & 15, khi = lane >> 4;

    f32x4 acc[4][2];
#pragma unroll
    for (int mt = 0; mt < 4; ++mt)
#pragma unroll
        for (int ntl = 0; ntl < 2; ++ntl)
#pragma unroll
            for (int q = 0; q < 4; ++q) acc[mt][ntl][q] = 0.f;

    float xa[FIN];
    __syncthreads();

    for (int h = 0; h < H1; ++h) {
        // per-head xa reload from LDS (2-way bank alias: free)
#pragma unroll
        for (int f = 0; f < FIN; ++f) xa[f] = xagg_s[row * 97 + h * FIN + f];

        for (int half = 0; half < 2; ++half) {
            const int k0 = (h << 7) + (half << 6);
            // wave-uniform W1/b1 column base -> scalar loads
            const float* w1s = W1 + (size_t)(k0 + wvu * 16);
            const float* b1s = b1 + (k0 + wvu * 16);
            float z[16];
#pragma unroll
            for (int c = 0; c < 16; ++c) z[c] = b1s[c];
#pragma unroll
            for (int f = 0; f < FIN; ++f) {
#pragma unroll
                for (int c = 0; c < 16; ++c)
                    z[c] = fmaf(xa[f], w1s[(size_t)f * KK + c], z[c]);
            }
            // ELU + pack bf16 pairs
            unsigned int pk[8];
#pragma unroll
            for (int p = 0; p < 8; ++p) {
                float lo = z[2 * p],     hi = z[2 * p + 1];
                lo = lo > 0.f ? lo : __expf(lo) - 1.f;
                hi = hi > 0.f ? hi : __expf(hi) - 1.f;
                pk[p] = (unsigned int)f2bf(lo) | ((unsigned int)f2bf(hi) << 16);
            }
            __syncthreads();              // prev-iter Xs reads done
#pragma unroll
            for (int j = 0; j < 2; ++j) {
                int g = wvu * 2 + j;      // granule (8 cols)
                uint4 v = make_uint4(pk[j * 4 + 0], pk[j * 4 + 1], pk[j * 4 + 2], pk[j * 4 + 3]);
                *(uint4*)&Xs[row * 64 + ((g ^ (row & 7)) << 3)] = v;
            }
            __syncthreads();
            // main MFMA: 2 K-subtiles x 4 row-tiles x 2 col-tiles
#pragma unroll
            for (int ks = 0; ks < 2; ++ks) {
                const int ktabs = (k0 >> 5) + ks;
                short8v bfr[2];
#pragma unroll
                for (int ntl = 0; ntl < 2; ++ntl) {
                    const int nt = wvu * 2 + ntl;
                    bfr[ntl] = *(const short8v*)&W2p[(((size_t)ktabs * 8 + nt) * 64 + lane) * 8];
                }
#pragma unroll
                for (int mt = 0; mt < 4; ++mt) {
                    const int row2 = mt * 16 + rlo;
                    const int gk = ks * 4 + khi;
                    short8v af = *(const short8v*)&Xs[row2 * 64 + ((gk ^ (row2 & 7)) << 3)];
                    acc[mt][0] = __builtin_amdgcn_mfma_f32_16x16x32_bf16(af, bfr[0], acc[mt][0], 0, 0, 0);
                    acc[mt][1] = __builtin_amdgcn_mfma_f32_16x16x32_bf16(af, bfr[1], acc[mt][1], 0, 0, 0);
                }
            }
        }
    }
    // C write: col = lane&15, row = (lane>>4)*4 + reg   (m89-verified layout)
#pragma unroll
    for (int mt = 0; mt < 4; ++mt)
#pragma unroll
        for (int ntl = 0; ntl < 2; ++ntl)
#pragma unroll
            for (int q = 0; q < 4; ++q) {
                int r2 = n0 + mt * 16 + khi * 4 + q;
                int c2 = wvu * 32 + ntl * 16 + rlo;
                h2[(size_t)r2 * DD + c2] = acc[mt][ntl][q];
            }
}

// ---- layer-2 logits (32 lanes per node, shuffle reduce) ---------------------
__global__ void alpha2_kernel(const float* __restrict__ h2,
                              const float* __restrict__ a_src2,
                              const float* __restrict__ a_dst2,
                              float* __restrict__ as2, float* __restrict__ ad2) {
    int gid = blockIdx.x * 256 + threadIdx.x;
    int n = gid >> 5, lane = gid & 31;
    if (n >= NN) return;
    float4 hv = *(const float4*)&h2[(size_t)n * DD + lane * 4];
    float4 sa = *(const float4*)&a_src2[lane * 4];
    float4 da = *(const float4*)&a_dst2[lane * 4];
    float s = hv.x * sa.x + hv.y * sa.y + hv.z * sa.z + hv.w * sa.w;
    float d = hv.x * da.x + hv.y * da.y + hv.z * da.z + hv.w * da.w;
#pragma unroll
    for (int o = 16; o > 0; o >>= 1) {
        s += __shfl_xor(s, o, 32);
        d += __shfl_xor(d, o, 32);
    }
    if (lane == 0) { as2[n] = s; ad2[n] = d; }
}

// ---- layer-2 aggregation: gather-side, 32 lanes per dst node ----------------
__global__ void agg2_kernel(const int* __restrict__ rowptr, const int* __restrict__ elist,
                            const float* __restrict__ h2,
                            const float* __restrict__ as2, const float* __restrict__ ad2,
                            const float* __restrict__ b2, float* __restrict__ x2) {
    int gid = blockIdx.x * 256 + threadIdx.x;
    int n = gid >> 5, lane = gid & 31;
    if (n >= NN) return;
    int beg = rowptr[n], end = rowptr[n + 1];
    float adn = ad2[n];
    float m = -INFINITY;
    for (int j = beg; j < end; ++j)
        m = fmaxf(m, lrelu(as2[elist[j]] + adn));
    float den = 0.f;
    float4 acc = make_float4(0.f, 0.f, 0.f, 0.f);
    for (int j = beg; j < end; ++j) {
        int s = elist[j];
        float ex = expf(lrelu(as2[s] + adn) - m);
        den += ex;
        float4 hv = *(const float4*)&h2[(size_t)s * DD + lane * 4];
        acc.x = fmaf(ex, hv.x, acc.x);
        acc.y = fmaf(ex, hv.y, acc.y);
        acc.z = fmaf(ex, hv.z, acc.z);
        acc.w = fmaf(ex, hv.w, acc.w);
    }
    float inv = 1.f / (den + 1e-16f);
    float4 bv = *(const float4*)&b2[lane * 4];
    float4 r;
    r.x = eluf(acc.x * inv + bv.x);
    r.y = eluf(acc.y * inv + bv.y);
    r.z = eluf(acc.z * inv + bv.z);
    r.w = eluf(acc.w * inv + bv.w);
    *(float4*)&x2[(size_t)n * DD + lane * 4] = r;
}

// ---- pooling: one block per graph over its contiguous node range ------------
__global__ void pool_kernel(const int* __restrict__ gptr, const float* __restrict__ x2,
                            float* __restrict__ pooled) {
    int g = blockIdx.x;
    int c = threadIdx.x;          // 128 channels
    int beg = gptr[g], end = gptr[g + 1];
    float v = -INFINITY;
    for (int n = beg; n < end; ++n)
        v = fmaxf(v, x2[(size_t)n * DD + c]);
    if (beg == end) v = 0.f;      // empty graph -> 0 (isfinite guard)
    pooled[g * DD + c] = v;
}

// ---- out = relu(pooled @ Wfc + bfc) -----------------------------------------
__global__ void final_kernel(const float* __restrict__ pooled, const float* __restrict__ Wfc,
                             const float* __restrict__ bfc, float* __restrict__ out) {
    int idx = blockIdx.x * 256 + threadIdx.x;   // NG*DD
    int g = idx >> 7, c = idx & 127;
    float acc = bfc[c];
#pragma unroll 8
    for (int k = 0; k < DD; ++k)
        acc = fmaf(pooled[g * DD + k], Wfc[k * DD + c], acc);
    out[idx] = acc > 0.f ? acc : 0.f;
}

extern "C" void kernel_launch(void* const* d_in, const int* in_sizes, int n_in,
                              void* d_out, int out_size, void* d_ws, size_t ws_size,
                              hipStream_t stream) {
    const float* x      = (const float*)d_in[0];
    const int*   ei     = (const int*)d_in[1];
    const int*   batch  = (const int*)d_in[3];
    const float* W1     = (const float*)d_in[4];
    const float* a_src1 = (const float*)d_in[5];
    const float* a_dst1 = (const float*)d_in[6];
    const float* b1     = (const float*)d_in[7];
    const float* W2     = (const float*)d_in[8];
    const float* a_src2 = (const float*)d_in[9];
    const float* a_dst2 = (const float*)d_in[10];
    const float* b2     = (const float*)d_in[11];
    const float* Wfc    = (const float*)d_in[12];
    const float* bfc    = (const float*)d_in[13];
    float* out = (float*)d_out;

    // workspace layout — ~98 MB total
    float* wsf    = (float*)d_ws;
    float* ws1    = wsf;                                   // 96
    float* wd1    = ws1 + 96;                              // 96
    float* as1    = wd1 + 96;                              // NN*H1
    float* ad1    = as1 + (size_t)NN * H1;                 // NN*H1
    float* xaggn  = ad1 + (size_t)NN * H1;                 // NN*H1*FIN
    float* h2     = xaggn + (size_t)NN * H1 * FIN;         // NN*DD
    float* as2    = h2 + (size_t)NN * DD;                  // NN
    float* ad2    = as2 + NN;                              // NN
    float* x2     = ad2 + NN;                              // NN*DD
    float* pooled = x2 + (size_t)NN * DD;                  // NG*DD
    int*   deg    = (int*)(pooled + (size_t)NG * DD);      // NN
    int*   rowptr = deg + NN;                              // NN+1
    int*   cursor = rowptr + NN + 1;                       // NN
    int*   elist  = cursor + NN;                           // ET
    int*   gptr   = elist + ET;                            // NG+1
    // align W2p to 16 bytes
    size_t off = (size_t)((char*)(gptr + NG + 1) - (char*)d_ws);
    off = (off + 15) & ~(size_t)15;
    unsigned short* W2p = (unsigned short*)((char*)d_ws + off);  // KK*DD bf16

    prep_kernel   <<<1, 128, 0, stream>>>(W1, a_src1, a_dst1, ws1, wd1);
    packW2_kernel <<<(KK * DD + 255) / 256, 256, 0, stream>>>(W2, W2p);
    alpha1_kernel <<<NN / 256, 256, 0, stream>>>(x, ws1, wd1, as1, ad1, deg);
    count_kernel  <<<(ET + 255) / 256, 256, 0, stream>>>(ei, deg);
    scan_kernel   <<<1, 1024, 0, stream>>>(deg, rowptr, cursor);
    scatter_kernel<<<(ET + 255) / 256, 256, 0, stream>>>(ei, cursor, elist);
    gptr_kernel   <<<NN / 256, 256, 0, stream>>>(batch, gptr);
    agg1_kernel   <<<(NN * H1 + 255) / 256, 256, 0, stream>>>(rowptr, elist, x, as1, ad1, xaggn);
    h2_gemm       <<<NN / 64, 256, 0, stream>>>(xaggn, W1, b1, W2p, h2);
    alpha2_kernel <<<(NN * 32) / 256, 256, 0, stream>>>(h2, a_src2, a_dst2, as2, ad2);
    agg2_kernel   <<<(NN * 32) / 256, 256, 0, stream>>>(rowptr, elist, h2, as2, ad2, b2, x2);
    pool_kernel   <<<NG, 128, 0, stream>>>(gptr, x2, pooled);
    final_kernel  <<<(NG * DD) / 256, 256, 0, stream>>>(pooled, Wfc, bfc, out);
}